// Round 1
// baseline (3229.573 us; speedup 1.0000x reference)
//
#include <hip/hip_runtime.h>
#include <math.h>

#define LRELU(x) (fmaxf((x), 0.f) + 0.2f * fminf((x), 0.f))

// ---------------- CSR build ----------------
__global__ void deg_init_k(int* deg, int n) {
  int i = blockIdx.x * blockDim.x + threadIdx.x;
  if (i < n) deg[i] = 1;  // self loop
}

__global__ void deg_count_k(const int* __restrict__ dst, int* __restrict__ deg, int e) {
  int i = blockIdx.x * blockDim.x + threadIdx.x;
  if (i < e) atomicAdd(&deg[dst[i]], 1);
}

__global__ void scan_k(const int* __restrict__ deg, int* __restrict__ offsets,
                       int* __restrict__ cursor, int n) {
  __shared__ int sums[1024];
  int tid = threadIdx.x;
  int chunk = (n + 1023) >> 10;
  int base = tid * chunk;
  int s = 0;
  for (int i = 0; i < chunk; ++i) {
    int j = base + i;
    if (j < n) s += deg[j];
  }
  sums[tid] = s;
  __syncthreads();
  for (int off = 1; off < 1024; off <<= 1) {
    int v = (tid >= off) ? sums[tid - off] : 0;
    __syncthreads();
    sums[tid] += v;
    __syncthreads();
  }
  int run = sums[tid] - s;  // exclusive prefix for this thread's chunk
  for (int i = 0; i < chunk; ++i) {
    int j = base + i;
    if (j < n) {
      offsets[j] = run;
      cursor[j] = run;
      run += deg[j];
    }
  }
  if (tid == 1023) offsets[n] = sums[1023];
}

__global__ void csr_fill_k(const int* __restrict__ src, const int* __restrict__ dst,
                           int* __restrict__ cursor, int* __restrict__ csr_src,
                           int e, int n) {
  int i = blockIdx.x * blockDim.x + threadIdx.x;
  if (i >= e + n) return;
  int s, d;
  if (i < e) { s = src[i]; d = dst[i]; }
  else       { s = i - e;  d = s; }
  int pos = atomicAdd(&cursor[d], 1);
  csr_src[pos] = s;
}

// ---------------- BatchNorm (training-mode batch stats) ----------------
__global__ void col_stats_k(const float* __restrict__ h, int M, int D,
                            float* __restrict__ s1, float* __restrict__ s2) {
  int c = blockIdx.x * blockDim.x + threadIdx.x;
  if (c >= D) return;
  int rows = (M + gridDim.y - 1) / gridDim.y;
  int r0 = blockIdx.y * rows;
  int r1 = min(M, r0 + rows);
  float a = 0.f, b = 0.f;
  for (int r = r0; r < r1; ++r) {
    float v = h[(size_t)r * D + c];
    a += v;
    b += v * v;
  }
  atomicAdd(&s1[c], a);
  atomicAdd(&s2[c], b);
}

__global__ void bn_fin_k(const float* __restrict__ s1, const float* __restrict__ s2,
                         const float* __restrict__ g, const float* __restrict__ b,
                         float* __restrict__ acol, float* __restrict__ ccol,
                         int D, float invM) {
  int c = blockIdx.x * blockDim.x + threadIdx.x;
  if (c >= D) return;
  float m = s1[c] * invM;
  float v = fmaxf(s2[c] * invM - m * m, 0.f);
  float a = rsqrtf(v + 1e-5f) * g[c];
  acol[c] = a;
  ccol[c] = b[c] - m * a;
}

__global__ void bn_apply_relu_k(float* __restrict__ h, const float* __restrict__ acol,
                                const float* __restrict__ ccol, int M, int D) {
  size_t i = (size_t)blockIdx.x * blockDim.x + threadIdx.x;
  if (i >= (size_t)M * D) return;
  int c = (int)(i % D);
  float v = h[i] * acol[c] + ccol[c];
  h[i] = fmaxf(v, 0.f);
}

// ---------------- fp32 SGEMM: C[M,N] = (A .* ascale + ashift) @ B ----------------
// 128x128 tile, BK=16, 256 threads, 8x8 per thread. N must be multiple of 128.
__global__ __launch_bounds__(256)
void sgemm_k(const float* __restrict__ A, const float* __restrict__ B,
             float* __restrict__ C, int M, int N, int K,
             const float* __restrict__ ascale, const float* __restrict__ ashift) {
  __shared__ float As[16][132];
  __shared__ float Bs[16][128];
  int tid = threadIdx.x;
  int tx = tid & 15, ty = tid >> 4;
  int row0 = blockIdx.y * 128, col0 = blockIdx.x * 128;
  bool alignedA = ((K & 3) == 0);
  bool hasScale = (ascale != nullptr);

  float acc[8][8];
#pragma unroll
  for (int i = 0; i < 8; ++i)
#pragma unroll
    for (int j = 0; j < 8; ++j) acc[i][j] = 0.f;

  for (int kt = 0; kt < K; kt += 16) {
    // A tile: 128 rows x 16 k
#pragma unroll
    for (int i = 0; i < 2; ++i) {
      int idx = tid + i * 256;      // quad index 0..511
      int r = idx >> 2;
      int kq = (idx & 3) << 2;
      int grow = row0 + r;
      int gk = kt + kq;
      float va[4] = {0.f, 0.f, 0.f, 0.f};
      if (grow < M) {
        if (alignedA && gk + 4 <= K) {
          float4 t = *(const float4*)(A + (size_t)grow * K + gk);
          va[0] = t.x; va[1] = t.y; va[2] = t.z; va[3] = t.w;
        } else {
#pragma unroll
          for (int q = 0; q < 4; ++q)
            if (gk + q < K) va[q] = A[(size_t)grow * K + gk + q];
        }
        if (hasScale) {
#pragma unroll
          for (int q = 0; q < 4; ++q)
            if (gk + q < K) va[q] = va[q] * ascale[gk + q] + ashift[gk + q];
        }
      }
      As[kq + 0][r] = va[0];
      As[kq + 1][r] = va[1];
      As[kq + 2][r] = va[2];
      As[kq + 3][r] = va[3];
    }
    // B tile: 16 k x 128 cols  (N multiple of 128, rows k-guarded)
#pragma unroll
    for (int i = 0; i < 2; ++i) {
      int idx = tid + i * 256;
      int kr = idx >> 5;            // 0..15
      int cq = (idx & 31) << 2;     // 0..124
      float4 v = make_float4(0.f, 0.f, 0.f, 0.f);
      int gk = kt + kr;
      if (gk < K) v = *(const float4*)(B + (size_t)gk * N + col0 + cq);
      *(float4*)&Bs[kr][cq] = v;
    }
    __syncthreads();
#pragma unroll
    for (int k = 0; k < 16; ++k) {
      float a[8], b[8];
#pragma unroll
      for (int i = 0; i < 8; ++i) a[i] = As[k][ty * 8 + i];
#pragma unroll
      for (int j = 0; j < 8; ++j) b[j] = Bs[k][tx * 8 + j];
#pragma unroll
      for (int i = 0; i < 8; ++i)
#pragma unroll
        for (int j = 0; j < 8; ++j) acc[i][j] = fmaf(a[i], b[j], acc[i][j]);
    }
    __syncthreads();
  }
#pragma unroll
  for (int i = 0; i < 8; ++i) {
    int grow = row0 + ty * 8 + i;
    if (grow >= M) continue;
    float* cp = C + (size_t)grow * N + col0 + tx * 8;
#pragma unroll
    for (int j = 0; j < 8; j += 4) {
      float4 v = make_float4(acc[i][j], acc[i][j + 1], acc[i][j + 2], acc[i][j + 3]);
      *(float4*)(cp + j) = v;
    }
  }
}

// ---------------- Fused GATv2 edge kernel (one wave per node,head) ----------------
// C = 512 channels/head. Online softmax over incoming edges, then mean-div + bias.
template <int H>
__global__ __launch_bounds__(256)
void gat_edge_k(const float* __restrict__ xl, const float* __restrict__ xr,
                const float* __restrict__ att, const float* __restrict__ bias,
                const int* __restrict__ csr, const int* __restrict__ offsets,
                float* __restrict__ out, int n, int relu) {
  int gw = (blockIdx.x * 256 + threadIdx.x) >> 6;
  int lane = threadIdx.x & 63;
  if (gw >= n * H) return;
  int node = gw / H;
  int head = gw - node * H;
  const int W = H * 512;
  const size_t rowoff = (size_t)node * W + head * 512;
  int c0 = lane * 4;

  float4 xr0 = *(const float4*)(xr + rowoff + c0);
  float4 xr1 = *(const float4*)(xr + rowoff + c0 + 256);
  float4 at0 = *(const float4*)(att + head * 512 + c0);
  float4 at1 = *(const float4*)(att + head * 512 + c0 + 256);

  float m = -1e30f, l = 0.f;
  float4 acc0 = make_float4(0.f, 0.f, 0.f, 0.f);
  float4 acc1 = make_float4(0.f, 0.f, 0.f, 0.f);
  int p0 = offsets[node], p1 = offsets[node + 1];
  for (int p = p0; p < p1; ++p) {
    int s = csr[p];
    const float* xlp = xl + (size_t)s * W + head * 512;
    float4 v0 = *(const float4*)(xlp + c0);
    float4 v1 = *(const float4*)(xlp + c0 + 256);
    float e = LRELU(v0.x + xr0.x) * at0.x + LRELU(v0.y + xr0.y) * at0.y +
              LRELU(v0.z + xr0.z) * at0.z + LRELU(v0.w + xr0.w) * at0.w +
              LRELU(v1.x + xr1.x) * at1.x + LRELU(v1.y + xr1.y) * at1.y +
              LRELU(v1.z + xr1.z) * at1.z + LRELU(v1.w + xr1.w) * at1.w;
#pragma unroll
    for (int off = 32; off > 0; off >>= 1) e += __shfl_xor(e, off, 64);
    float mn = fmaxf(m, e);
    float corr = expf(m - mn);
    float w = expf(e - mn);
    l = l * corr + w;
    acc0.x = acc0.x * corr + w * v0.x;
    acc0.y = acc0.y * corr + w * v0.y;
    acc0.z = acc0.z * corr + w * v0.z;
    acc0.w = acc0.w * corr + w * v0.w;
    acc1.x = acc1.x * corr + w * v1.x;
    acc1.y = acc1.y * corr + w * v1.y;
    acc1.z = acc1.z * corr + w * v1.z;
    acc1.w = acc1.w * corr + w * v1.w;
    m = mn;
  }
  float inv = 1.f / (l * (float)(p1 - p0));
  float4 b0 = *(const float4*)(bias + head * 512 + c0);
  float4 b1 = *(const float4*)(bias + head * 512 + c0 + 256);
  float4 o0, o1;
  o0.x = acc0.x * inv + b0.x;
  o0.y = acc0.y * inv + b0.y;
  o0.z = acc0.z * inv + b0.z;
  o0.w = acc0.w * inv + b0.w;
  o1.x = acc1.x * inv + b1.x;
  o1.y = acc1.y * inv + b1.y;
  o1.z = acc1.z * inv + b1.z;
  o1.w = acc1.w * inv + b1.w;
  if (relu) {
    o0.x = fmaxf(o0.x, 0.f); o0.y = fmaxf(o0.y, 0.f);
    o0.z = fmaxf(o0.z, 0.f); o0.w = fmaxf(o0.w, 0.f);
    o1.x = fmaxf(o1.x, 0.f); o1.y = fmaxf(o1.y, 0.f);
    o1.z = fmaxf(o1.z, 0.f); o1.w = fmaxf(o1.w, 0.f);
  }
  *(float4*)(out + rowoff + c0) = o0;
  *(float4*)(out + rowoff + c0 + 256) = o1;
}

// ---------------- head: sigmoid(h @ Wh + bh) ----------------
__global__ __launch_bounds__(256)
void head_k(const float* __restrict__ h, const float* __restrict__ Wh,
            const float* __restrict__ bh, float* __restrict__ pred, int n) {
  int gw = (blockIdx.x * 256 + threadIdx.x) >> 6;
  int lane = threadIdx.x & 63;
  if (gw >= n) return;
  const float* hp = h + (size_t)gw * 512;
  int c0 = lane * 4;
  float4 a0 = *(const float4*)(hp + c0);
  float4 a1 = *(const float4*)(hp + c0 + 256);
  float4 w0 = *(const float4*)(Wh + c0);
  float4 w1 = *(const float4*)(Wh + c0 + 256);
  float s = a0.x * w0.x + a0.y * w0.y + a0.z * w0.z + a0.w * w0.w +
            a1.x * w1.x + a1.y * w1.y + a1.z * w1.z + a1.w * w1.w;
#pragma unroll
  for (int off = 32; off > 0; off >>= 1) s += __shfl_xor(s, off, 64);
  if (lane == 0) pred[gw] = 1.f / (1.f + expf(-(s + bh[0])));
}

__global__ void gather_k(const float* __restrict__ pred, const float* __restrict__ y,
                         const int* __restrict__ idx, float* __restrict__ out, int nt) {
  int i = blockIdx.x * blockDim.x + threadIdx.x;
  if (i >= nt) return;
  int j = idx[i];
  out[i] = pred[j];
  out[nt + i] = y[j];
}

// ---------------- launch ----------------
extern "C" void kernel_launch(void* const* d_in, const int* in_sizes, int n_in,
                              void* d_out, int out_size, void* d_ws, size_t ws_size,
                              hipStream_t stream) {
  const float* x     = (const float*)d_in[0];
  const int*   ei    = (const int*)d_in[1];
  const float* y     = (const float*)d_in[2];
  const int*   tidx  = (const int*)d_in[3];
  const float* bn0_g = (const float*)d_in[4];
  const float* bn0_b = (const float*)d_in[5];
  const float* W1l   = (const float*)d_in[6];
  const float* W1r   = (const float*)d_in[7];
  const float* a1    = (const float*)d_in[8];
  const float* b1    = (const float*)d_in[9];
  const float* bn1_g = (const float*)d_in[10];
  const float* bn1_b = (const float*)d_in[11];
  const float* W2l   = (const float*)d_in[12];
  const float* W2r   = (const float*)d_in[13];
  const float* a2    = (const float*)d_in[14];
  const float* b2    = (const float*)d_in[15];
  const float* bn2_g = (const float*)d_in[16];
  const float* bn2_b = (const float*)d_in[17];
  const float* W3l   = (const float*)d_in[18];
  const float* W3r   = (const float*)d_in[19];
  const float* a3    = (const float*)d_in[20];
  const float* b3    = (const float*)d_in[21];
  const float* bn3_g = (const float*)d_in[22];
  const float* bn3_b = (const float*)d_in[23];
  const float* W4l   = (const float*)d_in[24];
  const float* W4r   = (const float*)d_in[25];
  const float* a4    = (const float*)d_in[26];
  const float* b4    = (const float*)d_in[27];
  const float* Wh    = (const float*)d_in[28];
  const float* bh    = (const float*)d_in[29];
  float* out = (float*)d_out;

  const int n   = in_sizes[2];      // 8000
  const int E   = in_sizes[1] / 2;  // 64000
  const int FIN = in_sizes[4];      // 3201
  const int NT  = in_sizes[3];      // 4000
  const int ET  = E + n;

  float* fw = (float*)d_ws;
  size_t o = 0;
  float* xl   = fw + o; o += (size_t)n * 1024;
  float* xr   = fw + o; o += (size_t)n * 1024;
  float* h    = fw + o; o += (size_t)n * 1024;
  float* pred = fw + o; o += n;
  float* s1   = fw + o; o += 4096;
  float* s2   = fw + o; o += 4096;
  float* acol = fw + o; o += 4096;
  float* ccol = fw + o; o += 4096;
  int* deg     = (int*)(fw + o);
  int* offsets = deg + n;
  int* cursor  = offsets + n + 1;
  int* csr     = cursor + n;

  // CSR build (dst-sorted incoming edges incl. self loops)
  deg_init_k<<<(n + 255) / 256, 256, 0, stream>>>(deg, n);
  deg_count_k<<<(E + 255) / 256, 256, 0, stream>>>(ei + E, deg, E);
  scan_k<<<1, 1024, 0, stream>>>(deg, offsets, cursor, n);
  csr_fill_k<<<(ET + 255) / 256, 256, 0, stream>>>(ei, ei + E, cursor, csr, E, n);

  float invM = 1.f / (float)n;

  // BN0 (folded into GEMM1 A-load via acol/ccol)
  hipMemsetAsync(s1, 0, 2 * 4096 * sizeof(float), stream);
  {
    dim3 g((FIN + 255) / 256, 32);
    col_stats_k<<<g, 256, 0, stream>>>(x, n, FIN, s1, s2);
    bn_fin_k<<<(FIN + 255) / 256, 256, 0, stream>>>(s1, s2, bn0_g, bn0_b, acol, ccol, FIN, invM);
  }

  // Layer 1 (H=2, 3201 -> 1024)
  {
    dim3 g(1024 / 128, (n + 127) / 128);
    sgemm_k<<<g, 256, 0, stream>>>(x, W1l, xl, n, 1024, FIN, acol, ccol);
    sgemm_k<<<g, 256, 0, stream>>>(x, W1r, xr, n, 1024, FIN, acol, ccol);
  }
  gat_edge_k<2><<<(n * 2 + 3) / 4, 256, 0, stream>>>(xl, xr, a1, b1, csr, offsets, h, n, 0);

  hipMemsetAsync(s1, 0, 2 * 4096 * sizeof(float), stream);
  {
    dim3 g((1024 + 255) / 256, 32);
    col_stats_k<<<g, 256, 0, stream>>>(h, n, 1024, s1, s2);
    bn_fin_k<<<4, 256, 0, stream>>>(s1, s2, bn1_g, bn1_b, acol, ccol, 1024, invM);
    bn_apply_relu_k<<<(int)(((size_t)n * 1024 + 255) / 256), 256, 0, stream>>>(h, acol, ccol, n, 1024);
  }

  // Layer 2 (H=1, 1024 -> 512)
  {
    dim3 g(512 / 128, (n + 127) / 128);
    sgemm_k<<<g, 256, 0, stream>>>(h, W2l, xl, n, 512, 1024, nullptr, nullptr);
    sgemm_k<<<g, 256, 0, stream>>>(h, W2r, xr, n, 512, 1024, nullptr, nullptr);
  }
  gat_edge_k<1><<<(n + 3) / 4, 256, 0, stream>>>(xl, xr, a2, b2, csr, offsets, h, n, 0);

  hipMemsetAsync(s1, 0, 2 * 4096 * sizeof(float), stream);
  {
    dim3 g((512 + 255) / 256, 32);
    col_stats_k<<<g, 256, 0, stream>>>(h, n, 512, s1, s2);
    bn_fin_k<<<2, 256, 0, stream>>>(s1, s2, bn2_g, bn2_b, acol, ccol, 512, invM);
    bn_apply_relu_k<<<(int)(((size_t)n * 512 + 255) / 256), 256, 0, stream>>>(h, acol, ccol, n, 512);
  }

  // Layer 3 (H=1, 512 -> 512)
  {
    dim3 g(512 / 128, (n + 127) / 128);
    sgemm_k<<<g, 256, 0, stream>>>(h, W3l, xl, n, 512, 512, nullptr, nullptr);
    sgemm_k<<<g, 256, 0, stream>>>(h, W3r, xr, n, 512, 512, nullptr, nullptr);
  }
  gat_edge_k<1><<<(n + 3) / 4, 256, 0, stream>>>(xl, xr, a3, b3, csr, offsets, h, n, 0);

  hipMemsetAsync(s1, 0, 2 * 4096 * sizeof(float), stream);
  {
    dim3 g((512 + 255) / 256, 32);
    col_stats_k<<<g, 256, 0, stream>>>(h, n, 512, s1, s2);
    bn_fin_k<<<2, 256, 0, stream>>>(s1, s2, bn3_g, bn3_b, acol, ccol, 512, invM);
    bn_apply_relu_k<<<(int)(((size_t)n * 512 + 255) / 256), 256, 0, stream>>>(h, acol, ccol, n, 512);
  }

  // Layer 4 (H=1, 512 -> 512), relu fused into edge kernel
  {
    dim3 g(512 / 128, (n + 127) / 128);
    sgemm_k<<<g, 256, 0, stream>>>(h, W4l, xl, n, 512, 512, nullptr, nullptr);
    sgemm_k<<<g, 256, 0, stream>>>(h, W4r, xr, n, 512, 512, nullptr, nullptr);
  }
  gat_edge_k<1><<<(n + 3) / 4, 256, 0, stream>>>(xl, xr, a4, b4, csr, offsets, h, n, 1);

  // Head + gather
  head_k<<<(n + 3) / 4, 256, 0, stream>>>(h, Wh, bh, pred, n);
  gather_k<<<(NT + 255) / 256, 256, 0, stream>>>(pred, y, tidx, out, NT);
}

// Round 2
// 991.426 us; speedup vs baseline: 3.2575x; 3.2575x over previous
//
#include <hip/hip_runtime.h>
#include <math.h>

typedef __bf16 bf16x8 __attribute__((ext_vector_type(8)));
typedef float f32x4 __attribute__((ext_vector_type(4)));
typedef unsigned short ushort8 __attribute__((ext_vector_type(8)));

__device__ __forceinline__ float bf2f(unsigned short u) {
  union { unsigned int i; float f; } c; c.i = ((unsigned int)u) << 16; return c.f;
}
__device__ __forceinline__ unsigned short f2bf(float f) {
  union { float f; unsigned int i; } c; c.f = f;
  unsigned int r = (c.i + 0x7fffu + ((c.i >> 16) & 1u)) >> 16;
  return (unsigned short)r;
}

// ---------------- CSR build ----------------
__global__ void deg_init_k(int* deg, int n) {
  int i = blockIdx.x * blockDim.x + threadIdx.x;
  if (i < n) deg[i] = 1;  // self loop
}

__global__ void deg_count_k(const int* __restrict__ dst, int* __restrict__ deg, int e) {
  int i = blockIdx.x * blockDim.x + threadIdx.x;
  if (i < e) atomicAdd(&deg[dst[i]], 1);
}

__global__ void scan_k(const int* __restrict__ deg, int* __restrict__ offsets,
                       int* __restrict__ cursor, int n) {
  __shared__ int sums[1024];
  int tid = threadIdx.x;
  int chunk = (n + 1023) >> 10;
  int base = tid * chunk;
  int s = 0;
  for (int i = 0; i < chunk; ++i) {
    int j = base + i;
    if (j < n) s += deg[j];
  }
  sums[tid] = s;
  __syncthreads();
  for (int off = 1; off < 1024; off <<= 1) {
    int v = (tid >= off) ? sums[tid - off] : 0;
    __syncthreads();
    sums[tid] += v;
    __syncthreads();
  }
  int run = sums[tid] - s;
  for (int i = 0; i < chunk; ++i) {
    int j = base + i;
    if (j < n) {
      offsets[j] = run;
      cursor[j] = run;
      run += deg[j];
    }
  }
  if (tid == 1023) offsets[n] = sums[1023];
}

__global__ void csr_fill_k(const int* __restrict__ src, const int* __restrict__ dst,
                           int* __restrict__ cursor, int* __restrict__ csr_src,
                           int e, int n) {
  int i = blockIdx.x * blockDim.x + threadIdx.x;
  if (i >= e + n) return;
  int s, d;
  if (i < e) { s = src[i]; d = dst[i]; }
  else       { s = i - e;  d = s; }
  int pos = atomicAdd(&cursor[d], 1);
  csr_src[pos] = s;
}

// ---------------- BatchNorm stats ----------------
__global__ void col_stats_k(const float* __restrict__ h, int M, int D,
                            float* __restrict__ s1, float* __restrict__ s2) {
  int c = blockIdx.x * blockDim.x + threadIdx.x;
  if (c >= D) return;
  int rows = (M + gridDim.y - 1) / gridDim.y;
  int r0 = blockIdx.y * rows;
  int r1 = min(M, r0 + rows);
  float a = 0.f, b = 0.f;
  for (int r = r0; r < r1; ++r) {
    float v = h[(size_t)r * D + c];
    a += v;
    b += v * v;
  }
  atomicAdd(&s1[c], a);
  atomicAdd(&s2[c], b);
}

__global__ void col_stats_bf_k(const unsigned short* __restrict__ h, int M, int D,
                               float* __restrict__ s1, float* __restrict__ s2) {
  int c = blockIdx.x * blockDim.x + threadIdx.x;
  if (c >= D) return;
  int rows = (M + gridDim.y - 1) / gridDim.y;
  int r0 = blockIdx.y * rows;
  int r1 = min(M, r0 + rows);
  float a = 0.f, b = 0.f;
  for (int r = r0; r < r1; ++r) {
    float v = bf2f(h[(size_t)r * D + c]);
    a += v;
    b += v * v;
  }
  atomicAdd(&s1[c], a);
  atomicAdd(&s2[c], b);
}

__global__ void bn_fin_k(const float* __restrict__ s1, const float* __restrict__ s2,
                         const float* __restrict__ g, const float* __restrict__ b,
                         float* __restrict__ acol, float* __restrict__ ccol,
                         int D, float invM) {
  int c = blockIdx.x * blockDim.x + threadIdx.x;
  if (c >= D) return;
  float m = s1[c] * invM;
  float v = fmaxf(s2[c] * invM - m * m, 0.f);
  float a = rsqrtf(v + 1e-5f) * g[c];
  acol[c] = a;
  ccol[c] = b[c] - m * a;
}

// BN apply + ReLU, bf16 in -> bf16 out (next layer's GEMM A)
__global__ void bn_apply_bf_k(const unsigned short* __restrict__ h, const float* __restrict__ acol,
                              const float* __restrict__ ccol, unsigned short* __restrict__ outb,
                              int M, int D) {
  size_t i = (size_t)blockIdx.x * blockDim.x + threadIdx.x;
  if (i >= (size_t)M * D) return;
  int c = (int)(i % D);
  float v = bf2f(h[i]) * acol[c] + ccol[c];
  outb[i] = f2bf(fmaxf(v, 0.f));
}

// BN0 fold + fp32->bf16 convert, zero-padded K
__global__ void bn0_convert_k(const float* __restrict__ x, const float* __restrict__ acol,
                              const float* __restrict__ ccol, unsigned short* __restrict__ Abf,
                              int M, int K, int Kp) {
  size_t i = (size_t)blockIdx.x * blockDim.x + threadIdx.x;
  if (i >= (size_t)M * Kp) return;
  int c = (int)(i % Kp);
  int r = (int)(i / Kp);
  float v = 0.f;
  if (c < K) v = x[(size_t)r * K + c] * acol[c] + ccol[c];
  Abf[i] = f2bf(v);
}

// weight transpose-convert: W [K,N] fp32 -> WT [N,Kp] bf16, zero pad
__global__ __launch_bounds__(256)
void wconv_k(const float* __restrict__ W, unsigned short* __restrict__ WT,
             int K, int N, int Kp) {
  __shared__ float t[32][33];
  int n0 = blockIdx.x * 32, k0 = blockIdx.y * 32;
  int tx = threadIdx.x & 31, ty = threadIdx.x >> 5;  // 32 x 8
#pragma unroll
  for (int i = 0; i < 32; i += 8) {
    int k = k0 + ty + i, nn = n0 + tx;
    t[ty + i][tx] = (k < K && nn < N) ? W[(size_t)k * N + nn] : 0.f;
  }
  __syncthreads();
#pragma unroll
  for (int i = 0; i < 32; i += 8) {
    int nn = n0 + ty + i, k = k0 + tx;
    if (nn < N && k < Kp) WT[(size_t)nn * Kp + k] = f2bf(t[tx][ty + i]);
  }
}

// ---------------- bf16 MFMA GEMM: C[M,N](bf16) = A[M,K](bf16) @ Bt[N,K](bf16)^T ----
// 128x128 tile, BK=64, 256 threads = 4 waves in 2x2, 4x4 of 16x16x32 MFMA per wave.
// K must be a multiple of 64; N a multiple of 128. A rows clamped to M-1 (stores guarded).
// LDS granule swizzle: granule (r,g) at slot r*8 + (g ^ (r&7))  -> 2-way bank alias on
// ds_read_b128 (free), while global_load_lds dest stays base+lane*16 contiguous.
__global__ __launch_bounds__(256)
void gemm_bf16_k(const unsigned short* __restrict__ A,
                 const unsigned short* __restrict__ Bt,
                 unsigned short* __restrict__ C, int M, int N, int K) {
  __shared__ unsigned short sA[128 * 64];
  __shared__ unsigned short sB[128 * 64];
  const int tid = threadIdx.x;
  const int wave = tid >> 6, lane = tid & 63;
  const int wm = wave >> 1, wn = wave & 1;
  const int l16 = lane & 15, lq = lane >> 4;
  const int row0 = blockIdx.y * 128, col0 = blockIdx.x * 128;

  f32x4 acc[4][4] = {};

  for (int kt = 0; kt < K; kt += 64) {
#pragma unroll
    for (int i = 0; i < 4; ++i) {
      int s = i * 256 + tid;
      int r = s >> 3;
      int g = (s & 7) ^ (r & 7);
      int ra = row0 + r;
      ra = ra < M ? ra : M - 1;
      const unsigned short* ga = A + (size_t)ra * K + (kt + g * 8);
      __builtin_amdgcn_global_load_lds(
          (const __attribute__((address_space(1))) void*)ga,
          (__attribute__((address_space(3))) void*)&sA[s * 8], 16, 0, 0);
      const unsigned short* gb = Bt + (size_t)(col0 + r) * K + (kt + g * 8);
      __builtin_amdgcn_global_load_lds(
          (const __attribute__((address_space(1))) void*)gb,
          (__attribute__((address_space(3))) void*)&sB[s * 8], 16, 0, 0);
    }
    __syncthreads();
#pragma unroll
    for (int ks = 0; ks < 2; ++ks) {
      bf16x8 af[4], bff[4];
#pragma unroll
      for (int t = 0; t < 4; ++t) {
        int g = ks * 4 + lq;
        int r = wm * 64 + t * 16 + l16;
        af[t] = *(const bf16x8*)&sA[(r * 8 + (g ^ (r & 7))) * 8];
        int rb = wn * 64 + t * 16 + l16;
        bff[t] = *(const bf16x8*)&sB[(rb * 8 + (g ^ (rb & 7))) * 8];
      }
#pragma unroll
      for (int mt = 0; mt < 4; ++mt)
#pragma unroll
        for (int nt = 0; nt < 4; ++nt)
          acc[mt][nt] = __builtin_amdgcn_mfma_f32_16x16x32_bf16(af[mt], bff[nt], acc[mt][nt], 0, 0, 0);
    }
    __syncthreads();
  }
  // C/D layout: col = lane&15, row = (lane>>4)*4 + reg  (m89/m91 verified)
#pragma unroll
  for (int mt = 0; mt < 4; ++mt) {
    int rbase = row0 + wm * 64 + mt * 16 + lq * 4;
#pragma unroll
    for (int nt = 0; nt < 4; ++nt) {
      int col = col0 + wn * 64 + nt * 16 + l16;
#pragma unroll
      for (int r = 0; r < 4; ++r) {
        int rr = rbase + r;
        if (rr < M) C[(size_t)rr * N + col] = f2bf(acc[mt][nt][r]);
      }
    }
  }
}

// ---------------- Fused GATv2 edge kernel (one wave per node,head), bf16 io ----------
template <int H>
__global__ __launch_bounds__(256)
void gat_edge_k(const unsigned short* __restrict__ xl, const unsigned short* __restrict__ xr,
                const float* __restrict__ att, const float* __restrict__ bias,
                const int* __restrict__ csr, const int* __restrict__ offsets,
                unsigned short* __restrict__ out, int n, int relu) {
  int gw = (blockIdx.x * 256 + threadIdx.x) >> 6;
  int lane = threadIdx.x & 63;
  if (gw >= n * H) return;
  int node = gw / H;
  int head = gw - node * H;
  const int W = H * 512;
  const size_t rowoff = (size_t)node * W + head * 512;
  int c0 = lane * 8;

  float xrv[8], atv[8];
  {
    ushort8 u = *(const ushort8*)(xr + rowoff + c0);
    const float* ap = att + head * 512 + c0;
#pragma unroll
    for (int j = 0; j < 8; ++j) { xrv[j] = bf2f(u[j]); atv[j] = ap[j]; }
  }
  float m = -1e30f, l = 0.f;
  float acc[8];
#pragma unroll
  for (int j = 0; j < 8; ++j) acc[j] = 0.f;
  int p0 = offsets[node], p1 = offsets[node + 1];
  for (int p = p0; p < p1; ++p) {
    int s = csr[p];
    ushort8 u = *(const ushort8*)(xl + (size_t)s * W + head * 512 + c0);
    float lv[8];
    float e = 0.f;
#pragma unroll
    for (int j = 0; j < 8; ++j) {
      lv[j] = bf2f(u[j]);
      float z = lv[j] + xrv[j];
      z = fmaxf(z, 0.f) + 0.2f * fminf(z, 0.f);
      e = fmaf(z, atv[j], e);
    }
#pragma unroll
    for (int off = 32; off > 0; off >>= 1) e += __shfl_xor(e, off, 64);
    float mn = fmaxf(m, e);
    float corr = __expf(m - mn);
    float w = __expf(e - mn);
    l = l * corr + w;
#pragma unroll
    for (int j = 0; j < 8; ++j) acc[j] = acc[j] * corr + w * lv[j];
    m = mn;
  }
  float inv = 1.f / (l * (float)(p1 - p0));
  const float* bp = bias + head * 512 + c0;
  ushort8 o;
#pragma unroll
  for (int j = 0; j < 8; ++j) {
    float v = acc[j] * inv + bp[j];
    if (relu) v = fmaxf(v, 0.f);
    o[j] = f2bf(v);
  }
  *(ushort8*)(out + rowoff + c0) = o;
}

// ---------------- head: sigmoid(h @ Wh + bh) ----------------
__global__ __launch_bounds__(256)
void head_k(const unsigned short* __restrict__ h, const float* __restrict__ Wh,
            const float* __restrict__ bh, float* __restrict__ pred, int n) {
  int gw = (blockIdx.x * 256 + threadIdx.x) >> 6;
  int lane = threadIdx.x & 63;
  if (gw >= n) return;
  ushort8 u = *(const ushort8*)(h + (size_t)gw * 512 + lane * 8);
  const float* wp = Wh + lane * 8;
  float s = 0.f;
#pragma unroll
  for (int j = 0; j < 8; ++j) s = fmaf(bf2f(u[j]), wp[j], s);
#pragma unroll
  for (int off = 32; off > 0; off >>= 1) s += __shfl_xor(s, off, 64);
  if (lane == 0) pred[gw] = 1.f / (1.f + __expf(-(s + bh[0])));
}

__global__ void gather_k(const float* __restrict__ pred, const float* __restrict__ y,
                         const int* __restrict__ idx, float* __restrict__ out, int nt) {
  int i = blockIdx.x * blockDim.x + threadIdx.x;
  if (i >= nt) return;
  int j = idx[i];
  out[i] = pred[j];
  out[nt + i] = y[j];
}

// ---------------- launch ----------------
extern "C" void kernel_launch(void* const* d_in, const int* in_sizes, int n_in,
                              void* d_out, int out_size, void* d_ws, size_t ws_size,
                              hipStream_t stream) {
  const float* x     = (const float*)d_in[0];
  const int*   ei    = (const int*)d_in[1];
  const float* y     = (const float*)d_in[2];
  const int*   tidx  = (const int*)d_in[3];
  const float* bn0_g = (const float*)d_in[4];
  const float* bn0_b = (const float*)d_in[5];
  const float* W1l   = (const float*)d_in[6];
  const float* W1r   = (const float*)d_in[7];
  const float* a1    = (const float*)d_in[8];
  const float* b1    = (const float*)d_in[9];
  const float* bn1_g = (const float*)d_in[10];
  const float* bn1_b = (const float*)d_in[11];
  const float* W2l   = (const float*)d_in[12];
  const float* W2r   = (const float*)d_in[13];
  const float* a2    = (const float*)d_in[14];
  const float* b2    = (const float*)d_in[15];
  const float* bn2_g = (const float*)d_in[16];
  const float* bn2_b = (const float*)d_in[17];
  const float* W3l   = (const float*)d_in[18];
  const float* W3r   = (const float*)d_in[19];
  const float* a3    = (const float*)d_in[20];
  const float* b3    = (const float*)d_in[21];
  const float* bn3_g = (const float*)d_in[22];
  const float* bn3_b = (const float*)d_in[23];
  const float* W4l   = (const float*)d_in[24];
  const float* W4r   = (const float*)d_in[25];
  const float* a4    = (const float*)d_in[26];
  const float* b4    = (const float*)d_in[27];
  const float* Wh    = (const float*)d_in[28];
  const float* bh    = (const float*)d_in[29];
  float* out = (float*)d_out;

  const int n   = in_sizes[2];      // 8000
  const int E   = in_sizes[1] / 2;  // 64000
  const int FIN = in_sizes[4];      // 3201
  const int NT  = in_sizes[3];      // 4000
  const int ET  = E + n;
  const int KP1 = 3264;             // FIN padded to mult of 64

  // ---- workspace layout (ushorts for bf16 regions) ----
  unsigned short* us = (unsigned short*)d_ws;
  const size_t ABF_SZ = (size_t)n * KP1;      // 26,112,000
  unsigned short* Abf = us;                   // GEMM A (bf16); layers 2-4 use [0, n*1024)
  unsigned short* hb  = us + ABF_SZ;          // h bf16 [n,1024 max]; hosts W1T pair pre-edge1
  unsigned short* xlb = hb + (size_t)n * 1024;
  unsigned short* xrb = xlb + (size_t)n * 1024;
  float* fp = (float*)(xrb + (size_t)n * 1024);
  float* pred = fp;            fp += n;
  float* s1   = fp;            fp += 4096;
  float* s2   = fp;            fp += 4096;
  float* acol = fp;            fp += 4096;
  float* ccol = fp;            fp += 4096;
  int* deg     = (int*)fp;
  int* offsets = deg + n;
  int* cursor  = offsets + n + 1;
  int* csr     = cursor + n;
  // weight bf16 regions (aliased into dead zones)
  unsigned short* W1lT = hb;                          // 1024*3264
  unsigned short* W1rT = hb + (size_t)1024 * KP1;
  unsigned short* WlT  = Abf + (size_t)n * 1024;      // layers 2-4: beyond live A
  // (per-layer Wr follows Wl contiguously)

  // ---- CSR build ----
  deg_init_k<<<(n + 255) / 256, 256, 0, stream>>>(deg, n);
  deg_count_k<<<(E + 255) / 256, 256, 0, stream>>>(ei + E, deg, E);
  scan_k<<<1, 1024, 0, stream>>>(deg, offsets, cursor, n);
  csr_fill_k<<<(ET + 255) / 256, 256, 0, stream>>>(ei, ei + E, cursor, csr, E, n);

  float invM = 1.f / (float)n;

  // ---- BN0 stats + fold into bf16 A ----
  hipMemsetAsync(s1, 0, 2 * 4096 * sizeof(float), stream);
  {
    dim3 g((FIN + 255) / 256, 32);
    col_stats_k<<<g, 256, 0, stream>>>(x, n, FIN, s1, s2);
    bn_fin_k<<<(FIN + 255) / 256, 256, 0, stream>>>(s1, s2, bn0_g, bn0_b, acol, ccol, FIN, invM);
  }
  bn0_convert_k<<<(int)((ABF_SZ + 255) / 256), 256, 0, stream>>>(x, acol, ccol, Abf, n, FIN, KP1);

  // ---- Layer 1 (H=2, 3264 -> 1024) ----
  {
    dim3 gw1(1024 / 32, KP1 / 32);
    wconv_k<<<gw1, 256, 0, stream>>>(W1l, W1lT, FIN, 1024, KP1);
    wconv_k<<<gw1, 256, 0, stream>>>(W1r, W1rT, FIN, 1024, KP1);
    dim3 g(1024 / 128, (n + 127) / 128);
    gemm_bf16_k<<<g, 256, 0, stream>>>(Abf, W1lT, xlb, n, 1024, KP1);
    gemm_bf16_k<<<g, 256, 0, stream>>>(Abf, W1rT, xrb, n, 1024, KP1);
  }
  gat_edge_k<2><<<(n * 2 + 3) / 4, 256, 0, stream>>>(xlb, xrb, a1, b1, csr, offsets, hb, n, 0);

  hipMemsetAsync(s1, 0, 2 * 4096 * sizeof(float), stream);
  {
    dim3 g(1024 / 256, 32);
    col_stats_bf_k<<<g, 256, 0, stream>>>(hb, n, 1024, s1, s2);
    bn_fin_k<<<4, 256, 0, stream>>>(s1, s2, bn1_g, bn1_b, acol, ccol, 1024, invM);
    bn_apply_bf_k<<<(int)(((size_t)n * 1024 + 255) / 256), 256, 0, stream>>>(hb, acol, ccol, Abf, n, 1024);
  }

  // ---- Layer 2 (H=1, 1024 -> 512) ----
  {
    dim3 gw2(512 / 32, 1024 / 32);
    wconv_k<<<gw2, 256, 0, stream>>>(W2l, WlT, 1024, 512, 1024);
    wconv_k<<<gw2, 256, 0, stream>>>(W2r, WlT + (size_t)512 * 1024, 1024, 512, 1024);
    dim3 g(512 / 128, (n + 127) / 128);
    gemm_bf16_k<<<g, 256, 0, stream>>>(Abf, WlT, xlb, n, 512, 1024);
    gemm_bf16_k<<<g, 256, 0, stream>>>(Abf, WlT + (size_t)512 * 1024, xrb, n, 512, 1024);
  }
  gat_edge_k<1><<<(n + 3) / 4, 256, 0, stream>>>(xlb, xrb, a2, b2, csr, offsets, hb, n, 0);

  hipMemsetAsync(s1, 0, 2 * 4096 * sizeof(float), stream);
  {
    dim3 g(512 / 256, 32);
    col_stats_bf_k<<<g, 256, 0, stream>>>(hb, n, 512, s1, s2);
    bn_fin_k<<<2, 256, 0, stream>>>(s1, s2, bn2_g, bn2_b, acol, ccol, 512, invM);
    bn_apply_bf_k<<<(int)(((size_t)n * 512 + 255) / 256), 256, 0, stream>>>(hb, acol, ccol, Abf, n, 512);
  }

  // ---- Layer 3 (H=1, 512 -> 512) ----
  {
    dim3 gw3(512 / 32, 512 / 32);
    wconv_k<<<gw3, 256, 0, stream>>>(W3l, WlT, 512, 512, 512);
    wconv_k<<<gw3, 256, 0, stream>>>(W3r, WlT + (size_t)512 * 512, 512, 512, 512);
    dim3 g(512 / 128, (n + 127) / 128);
    gemm_bf16_k<<<g, 256, 0, stream>>>(Abf, WlT, xlb, n, 512, 512);
    gemm_bf16_k<<<g, 256, 0, stream>>>(Abf, WlT + (size_t)512 * 512, xrb, n, 512, 512);
  }
  gat_edge_k<1><<<(n + 3) / 4, 256, 0, stream>>>(xlb, xrb, a3, b3, csr, offsets, hb, n, 0);

  hipMemsetAsync(s1, 0, 2 * 4096 * sizeof(float), stream);
  {
    dim3 g(512 / 256, 32);
    col_stats_bf_k<<<g, 256, 0, stream>>>(hb, n, 512, s1, s2);
    bn_fin_k<<<2, 256, 0, stream>>>(s1, s2, bn3_g, bn3_b, acol, ccol, 512, invM);
    bn_apply_bf_k<<<(int)(((size_t)n * 512 + 255) / 256), 256, 0, stream>>>(hb, acol, ccol, Abf, n, 512);
  }

  // ---- Layer 4 (H=1, 512 -> 512), relu fused into edge kernel ----
  {
    dim3 gw4(512 / 32, 512 / 32);
    wconv_k<<<gw4, 256, 0, stream>>>(W4l, WlT, 512, 512, 512);
    wconv_k<<<gw4, 256, 0, stream>>>(W4r, WlT + (size_t)512 * 512, 512, 512, 512);
    dim3 g(512 / 128, (n + 127) / 128);
    gemm_bf16_k<<<g, 256, 0, stream>>>(Abf, WlT, xlb, n, 512, 512);
    gemm_bf16_k<<<g, 256, 0, stream>>>(Abf, WlT + (size_t)512 * 512, xrb, n, 512, 512);
  }
  gat_edge_k<1><<<(n + 3) / 4, 256, 0, stream>>>(xlb, xrb, a4, b4, csr, offsets, hb, n, 1);

  // ---- head + gather ----
  head_k<<<(n + 3) / 4, 256, 0, stream>>>(hb, Wh, bh, pred, n);
  gather_k<<<(NT + 255) / 256, 256, 0, stream>>>(pred, y, tidx, out, NT);
}

// Round 3
// 832.803 us; speedup vs baseline: 3.8780x; 1.1905x over previous
//
#include <hip/hip_runtime.h>
#include <math.h>

typedef __bf16 bf16x8 __attribute__((ext_vector_type(8)));
typedef float f32x4 __attribute__((ext_vector_type(4)));
typedef unsigned short ushort8 __attribute__((ext_vector_type(8)));

__device__ __forceinline__ float bf2f(unsigned short u) {
  union { unsigned int i; float f; } c; c.i = ((unsigned int)u) << 16; return c.f;
}
__device__ __forceinline__ unsigned short f2bf(float f) {
  union { float f; unsigned int i; } c; c.f = f;
  unsigned int r = (c.i + 0x7fffu + ((c.i >> 16) & 1u)) >> 16;
  return (unsigned short)r;
}

// ---------------- CSR build ----------------
__global__ void deg_init_k(int* deg, int n) {
  int i = blockIdx.x * blockDim.x + threadIdx.x;
  if (i < n) deg[i] = 1;  // self loop
}

__global__ void deg_count_k(const int* __restrict__ dst, int* __restrict__ deg, int e) {
  int i = blockIdx.x * blockDim.x + threadIdx.x;
  if (i < e) atomicAdd(&deg[dst[i]], 1);
}

__global__ void scan_k(const int* __restrict__ deg, int* __restrict__ offsets,
                       int* __restrict__ cursor, int n) {
  __shared__ int sums[1024];
  int tid = threadIdx.x;
  int chunk = (n + 1023) >> 10;
  int base = tid * chunk;
  int s = 0;
  for (int i = 0; i < chunk; ++i) {
    int j = base + i;
    if (j < n) s += deg[j];
  }
  sums[tid] = s;
  __syncthreads();
  for (int off = 1; off < 1024; off <<= 1) {
    int v = (tid >= off) ? sums[tid - off] : 0;
    __syncthreads();
    sums[tid] += v;
    __syncthreads();
  }
  int run = sums[tid] - s;
  for (int i = 0; i < chunk; ++i) {
    int j = base + i;
    if (j < n) {
      offsets[j] = run;
      cursor[j] = run;
      run += deg[j];
    }
  }
  if (tid == 1023) offsets[n] = sums[1023];
}

__global__ void csr_fill_k(const int* __restrict__ src, const int* __restrict__ dst,
                           int* __restrict__ cursor, int* __restrict__ csr_src,
                           int e, int n) {
  int i = blockIdx.x * blockDim.x + threadIdx.x;
  if (i >= e + n) return;
  int s, d;
  if (i < e) { s = src[i]; d = dst[i]; }
  else       { s = i - e;  d = s; }
  int pos = atomicAdd(&cursor[d], 1);
  csr_src[pos] = s;
}

// ---------------- fused BN0 stats + fp32->bf16 raw convert (single pass over x) ----
__global__ __launch_bounds__(256)
void stats_convert_k(const float* __restrict__ x, unsigned short* __restrict__ Abf,
                     float* __restrict__ s1, float* __restrict__ s2,
                     int M, int K, int Kp) {
  int c = blockIdx.x * 256 + threadIdx.x;
  if (c >= Kp) return;
  int rows = (M + gridDim.y - 1) / gridDim.y;
  int r0 = blockIdx.y * rows;
  int r1 = min(M, r0 + rows);
  if (c >= K) {  // zero pad columns
    for (int r = r0; r < r1; ++r) Abf[(size_t)r * Kp + c] = 0;
    return;
  }
  float a = 0.f, b = 0.f;
  int r = r0;
  for (; r + 4 <= r1; r += 4) {
    float v0 = x[(size_t)(r + 0) * K + c];
    float v1 = x[(size_t)(r + 1) * K + c];
    float v2 = x[(size_t)(r + 2) * K + c];
    float v3 = x[(size_t)(r + 3) * K + c];
    a += v0 + v1 + v2 + v3;
    b += v0 * v0 + v1 * v1 + v2 * v2 + v3 * v3;
    Abf[(size_t)(r + 0) * Kp + c] = f2bf(v0);
    Abf[(size_t)(r + 1) * Kp + c] = f2bf(v1);
    Abf[(size_t)(r + 2) * Kp + c] = f2bf(v2);
    Abf[(size_t)(r + 3) * Kp + c] = f2bf(v3);
  }
  for (; r < r1; ++r) {
    float v = x[(size_t)r * K + c];
    a += v; b += v * v;
    Abf[(size_t)r * Kp + c] = f2bf(v);
  }
  atomicAdd(&s1[c], a);
  atomicAdd(&s2[c], b);
}

// ---------------- bf16 column stats (vectorized-parallel) ----------------
__global__ __launch_bounds__(256)
void col_stats_bf_k(const unsigned short* __restrict__ h, int M, int D,
                    float* __restrict__ s1, float* __restrict__ s2) {
  int c = blockIdx.x * 256 + threadIdx.x;
  if (c >= D) return;
  int rows = (M + gridDim.y - 1) / gridDim.y;
  int r0 = blockIdx.y * rows;
  int r1 = min(M, r0 + rows);
  float a = 0.f, b = 0.f;
  int r = r0;
  for (; r + 4 <= r1; r += 4) {
    float v0 = bf2f(h[(size_t)(r + 0) * D + c]);
    float v1 = bf2f(h[(size_t)(r + 1) * D + c]);
    float v2 = bf2f(h[(size_t)(r + 2) * D + c]);
    float v3 = bf2f(h[(size_t)(r + 3) * D + c]);
    a += v0 + v1 + v2 + v3;
    b += v0 * v0 + v1 * v1 + v2 * v2 + v3 * v3;
  }
  for (; r < r1; ++r) {
    float v = bf2f(h[(size_t)r * D + c]);
    a += v; b += v * v;
  }
  atomicAdd(&s1[c], a);
  atomicAdd(&s2[c], b);
}

__global__ void bn_fin_k(const float* __restrict__ s1, const float* __restrict__ s2,
                         const float* __restrict__ g, const float* __restrict__ b,
                         float* __restrict__ acol, float* __restrict__ ccol,
                         int D, float invM) {
  int c = blockIdx.x * blockDim.x + threadIdx.x;
  if (c >= D) return;
  float m = s1[c] * invM;
  float v = fmaxf(s2[c] * invM - m * m, 0.f);
  float a = rsqrtf(v + 1e-5f) * g[c];
  acol[c] = a;
  ccol[c] = b[c] - m * a;
}

// BN apply + ReLU, bf16 -> bf16, ushort8 vectorized
__global__ __launch_bounds__(256)
void bn_apply8_k(const unsigned short* __restrict__ h, const float* __restrict__ acol,
                 const float* __restrict__ ccol, unsigned short* __restrict__ outb,
                 size_t total, int D) {
  size_t i = ((size_t)blockIdx.x * 256 + threadIdx.x) * 8;
  if (i >= total) return;
  ushort8 u = *(const ushort8*)(h + i);
  int c = (int)(i % (size_t)D);
  ushort8 o;
#pragma unroll
  for (int j = 0; j < 8; ++j) {
    float v = bf2f(u[j]) * acol[c + j] + ccol[c + j];
    o[j] = f2bf(fmaxf(v, 0.f));
  }
  *(ushort8*)(outb + i) = o;
}

// weight transpose-convert: W [K,N] fp32 -> WT [N,Kp] bf16, zero pad.
// Optional: scale row k by scale[k] (BN0 fold) and accumulate bias[n] += sum_k cshift[k]*W[k,n].
__global__ __launch_bounds__(256)
void wconv_k(const float* __restrict__ W, unsigned short* __restrict__ WT,
             int K, int N, int Kp,
             const float* __restrict__ scale, const float* __restrict__ cshift,
             float* __restrict__ bias) {
  __shared__ float t[32][33];
  int n0 = blockIdx.x * 32, k0 = blockIdx.y * 32;
  int tx = threadIdx.x & 31, ty = threadIdx.x >> 5;  // 32 x 8
  float bsum = 0.f;
#pragma unroll
  for (int i = 0; i < 32; i += 8) {
    int k = k0 + ty + i, nn = n0 + tx;
    float v = (k < K && nn < N) ? W[(size_t)k * N + nn] : 0.f;
    t[ty + i][tx] = v;
    if (cshift && k < K) bsum += cshift[k] * v;
  }
  if (cshift) atomicAdd(&bias[n0 + tx], bsum);
  __syncthreads();
#pragma unroll
  for (int i = 0; i < 32; i += 8) {
    int nn = n0 + ty + i, k = k0 + tx;
    if (nn < N && k < Kp) {
      float v = t[tx][ty + i];
      if (scale && k < K) v *= scale[k];
      WT[(size_t)nn * Kp + k] = f2bf(v);
    }
  }
}

// ---------------- bf16 MFMA GEMM: C = A[M,K] @ Bt[Ntot,K]^T (+bias row), split store --
// 128x128 tile, BK=64, 4 waves 2x2, 4x4 16x16x32 MFMA per wave. K%64==0, Ntot%128==0.
__global__ __launch_bounds__(256)
void gemm_bf16_k(const unsigned short* __restrict__ A,
                 const unsigned short* __restrict__ Bt,
                 unsigned short* __restrict__ outL, unsigned short* __restrict__ outR,
                 const float* __restrict__ bias, int M, int Nh, int K) {
  __shared__ unsigned short sA[128 * 64];
  __shared__ unsigned short sB[128 * 64];
  const int tid = threadIdx.x;
  const int wave = tid >> 6, lane = tid & 63;
  const int wm = wave >> 1, wn = wave & 1;
  const int l16 = lane & 15, lq = lane >> 4;
  const int row0 = blockIdx.y * 128, col0 = blockIdx.x * 128;

  f32x4 acc[4][4] = {};

  for (int kt = 0; kt < K; kt += 64) {
#pragma unroll
    for (int i = 0; i < 4; ++i) {
      int s = i * 256 + tid;
      int r = s >> 3;
      int g = (s & 7) ^ (r & 7);
      int ra = row0 + r;
      ra = ra < M ? ra : M - 1;
      const unsigned short* ga = A + (size_t)ra * K + (kt + g * 8);
      __builtin_amdgcn_global_load_lds(
          (const __attribute__((address_space(1))) void*)ga,
          (__attribute__((address_space(3))) void*)&sA[s * 8], 16, 0, 0);
      const unsigned short* gb = Bt + (size_t)(col0 + r) * K + (kt + g * 8);
      __builtin_amdgcn_global_load_lds(
          (const __attribute__((address_space(1))) void*)gb,
          (__attribute__((address_space(3))) void*)&sB[s * 8], 16, 0, 0);
    }
    __syncthreads();
#pragma unroll
    for (int ks = 0; ks < 2; ++ks) {
      bf16x8 af[4], bff[4];
#pragma unroll
      for (int t = 0; t < 4; ++t) {
        int g = ks * 4 + lq;
        int r = wm * 64 + t * 16 + l16;
        af[t] = *(const bf16x8*)&sA[(r * 8 + (g ^ (r & 7))) * 8];
        int rb = wn * 64 + t * 16 + l16;
        bff[t] = *(const bf16x8*)&sB[(rb * 8 + (g ^ (rb & 7))) * 8];
      }
#pragma unroll
      for (int mt = 0; mt < 4; ++mt)
#pragma unroll
        for (int nt = 0; nt < 4; ++nt)
          acc[mt][nt] = __builtin_amdgcn_mfma_f32_16x16x32_bf16(af[mt], bff[nt], acc[mt][nt], 0, 0, 0);
    }
    __syncthreads();
  }
  // C/D layout: col = lane&15, row = (lane>>4)*4 + reg
#pragma unroll
  for (int mt = 0; mt < 4; ++mt) {
    int rbase = row0 + wm * 64 + mt * 16 + lq * 4;
#pragma unroll
    for (int nt = 0; nt < 4; ++nt) {
      int col = col0 + wn * 64 + nt * 16 + l16;
      float bv = bias ? bias[col] : 0.f;
      unsigned short* base;
      int cc;
      if (col < Nh) { base = outL; cc = col; }
      else          { base = outR; cc = col - Nh; }
#pragma unroll
      for (int r = 0; r < 4; ++r) {
        int rr = rbase + r;
        if (rr < M) base[(size_t)rr * Nh + cc] = f2bf(acc[mt][nt][r] + bv);
      }
    }
  }
}

// ---------------- Fused GATv2 edge kernel (one wave per node,head), bf16 io ----------
template <int H>
__global__ __launch_bounds__(256)
void gat_edge_k(const unsigned short* __restrict__ xl, const unsigned short* __restrict__ xr,
                const float* __restrict__ att, const float* __restrict__ bias,
                const int* __restrict__ csr, const int* __restrict__ offsets,
                unsigned short* __restrict__ out, int n, int relu) {
  int gw = (blockIdx.x * 256 + threadIdx.x) >> 6;
  int lane = threadIdx.x & 63;
  if (gw >= n * H) return;
  int node = gw / H;
  int head = gw - node * H;
  const int W = H * 512;
  const size_t rowoff = (size_t)node * W + head * 512;
  int c0 = lane * 8;

  float xrv[8], atv[8];
  {
    ushort8 u = *(const ushort8*)(xr + rowoff + c0);
    const float* ap = att + head * 512 + c0;
#pragma unroll
    for (int j = 0; j < 8; ++j) { xrv[j] = bf2f(u[j]); atv[j] = ap[j]; }
  }
  float m = -1e30f, l = 0.f;
  float acc[8];
#pragma unroll
  for (int j = 0; j < 8; ++j) acc[j] = 0.f;
  int p0 = offsets[node], p1 = offsets[node + 1];
  for (int p = p0; p < p1; ++p) {
    int s = csr[p];
    ushort8 u = *(const ushort8*)(xl + (size_t)s * W + head * 512 + c0);
    float lv[8];
    float e = 0.f;
#pragma unroll
    for (int j = 0; j < 8; ++j) {
      lv[j] = bf2f(u[j]);
      float z = lv[j] + xrv[j];
      z = fmaxf(z, 0.f) + 0.2f * fminf(z, 0.f);
      e = fmaf(z, atv[j], e);
    }
#pragma unroll
    for (int off = 32; off > 0; off >>= 1) e += __shfl_xor(e, off, 64);
    float mn = fmaxf(m, e);
    float corr = __expf(m - mn);
    float w = __expf(e - mn);
    l = l * corr + w;
#pragma unroll
    for (int j = 0; j < 8; ++j) acc[j] = acc[j] * corr + w * lv[j];
    m = mn;
  }
  float inv = 1.f / (l * (float)(p1 - p0));
  const float* bp = bias + head * 512 + c0;
  ushort8 o;
#pragma unroll
  for (int j = 0; j < 8; ++j) {
    float v = acc[j] * inv + bp[j];
    if (relu) v = fmaxf(v, 0.f);
    o[j] = f2bf(v);
  }
  *(ushort8*)(out + rowoff + c0) = o;
}

// ---------------- head: sigmoid(h @ Wh + bh) ----------------
__global__ __launch_bounds__(256)
void head_k(const unsigned short* __restrict__ h, const float* __restrict__ Wh,
            const float* __restrict__ bh, float* __restrict__ pred, int n) {
  int gw = (blockIdx.x * 256 + threadIdx.x) >> 6;
  int lane = threadIdx.x & 63;
  if (gw >= n) return;
  ushort8 u = *(const ushort8*)(h + (size_t)gw * 512 + lane * 8);
  const float* wp = Wh + lane * 8;
  float s = 0.f;
#pragma unroll
  for (int j = 0; j < 8; ++j) s = fmaf(bf2f(u[j]), wp[j], s);
#pragma unroll
  for (int off = 32; off > 0; off >>= 1) s += __shfl_xor(s, off, 64);
  if (lane == 0) pred[gw] = 1.f / (1.f + __expf(-(s + bh[0])));
}

__global__ void gather_k(const float* __restrict__ pred, const float* __restrict__ y,
                         const int* __restrict__ idx, float* __restrict__ out, int nt) {
  int i = blockIdx.x * blockDim.x + threadIdx.x;
  if (i >= nt) return;
  int j = idx[i];
  out[i] = pred[j];
  out[nt + i] = y[j];
}

// ---------------- launch ----------------
extern "C" void kernel_launch(void* const* d_in, const int* in_sizes, int n_in,
                              void* d_out, int out_size, void* d_ws, size_t ws_size,
                              hipStream_t stream) {
  const float* x     = (const float*)d_in[0];
  const int*   ei    = (const int*)d_in[1];
  const float* y     = (const float*)d_in[2];
  const int*   tidx  = (const int*)d_in[3];
  const float* bn0_g = (const float*)d_in[4];
  const float* bn0_b = (const float*)d_in[5];
  const float* W1l   = (const float*)d_in[6];
  const float* W1r   = (const float*)d_in[7];
  const float* a1    = (const float*)d_in[8];
  const float* b1    = (const float*)d_in[9];
  const float* bn1_g = (const float*)d_in[10];
  const float* bn1_b = (const float*)d_in[11];
  const float* W2l   = (const float*)d_in[12];
  const float* W2r   = (const float*)d_in[13];
  const float* a2    = (const float*)d_in[14];
  const float* b2    = (const float*)d_in[15];
  const float* bn2_g = (const float*)d_in[16];
  const float* bn2_b = (const float*)d_in[17];
  const float* W3l   = (const float*)d_in[18];
  const float* W3r   = (const float*)d_in[19];
  const float* a3    = (const float*)d_in[20];
  const float* b3    = (const float*)d_in[21];
  const float* bn3_g = (const float*)d_in[22];
  const float* bn3_b = (const float*)d_in[23];
  const float* W4l   = (const float*)d_in[24];
  const float* W4r   = (const float*)d_in[25];
  const float* a4    = (const float*)d_in[26];
  const float* b4    = (const float*)d_in[27];
  const float* Wh    = (const float*)d_in[28];
  const float* bh    = (const float*)d_in[29];
  float* out = (float*)d_out;

  const int n   = in_sizes[2];      // 8000
  const int E   = in_sizes[1] / 2;  // 64000
  const int FIN = in_sizes[4];      // 3201
  const int NT  = in_sizes[3];      // 4000
  const int ET  = E + n;
  const int KP1 = 3264;             // FIN padded to mult of 64

  // ---- workspace layout ----
  unsigned short* us = (unsigned short*)d_ws;
  const size_t ABF_SZ = (size_t)n * KP1;
  unsigned short* Abf = us;                   // GEMM A (bf16)
  unsigned short* hb  = us + ABF_SZ;          // h bf16; hosts W1T pair pre-edge1
  unsigned short* xlb = hb + (size_t)n * 1024;
  unsigned short* xrb = xlb + (size_t)n * 1024;
  float* fp = (float*)(xrb + (size_t)n * 1024);
  float* pred  = fp;           fp += n;
  float* s1    = fp;           fp += 4096;
  float* s2    = fp;           fp += 4096;
  float* acol  = fp;           fp += 4096;
  float* ccol  = fp;           fp += 4096;
  float* biasb = fp;           fp += 4096;
  int* deg     = (int*)fp;
  int* offsets = deg + n;
  int* cursor  = offsets + n + 1;
  int* csr     = cursor + n;
  unsigned short* W1lT = hb;                          // [2048, KP1] combined Bt
  unsigned short* WlT  = Abf + (size_t)n * 1024;      // layers 2-4 combined Bt

  // ---- CSR build ----
  deg_init_k<<<(n + 255) / 256, 256, 0, stream>>>(deg, n);
  deg_count_k<<<(E + 255) / 256, 256, 0, stream>>>(ei + E, deg, E);
  scan_k<<<1, 1024, 0, stream>>>(deg, offsets, cursor, n);
  csr_fill_k<<<(ET + 255) / 256, 256, 0, stream>>>(ei, ei + E, cursor, csr, E, n);

  float invM = 1.f / (float)n;

  // ---- BN0: fused stats + raw bf16 convert (single pass over x) ----
  hipMemsetAsync(s1, 0, 2 * 4096 * sizeof(float), stream);
  {
    dim3 g((KP1 + 255) / 256, 200);
    stats_convert_k<<<g, 256, 0, stream>>>(x, Abf, s1, s2, n, FIN, KP1);
    bn_fin_k<<<(FIN + 255) / 256, 256, 0, stream>>>(s1, s2, bn0_g, bn0_b, acol, ccol, FIN, invM);
  }

  // ---- Layer 1 (H=2, K=3264 -> N=2048 combined), BN0 folded into weights ----
  hipMemsetAsync(biasb, 0, 2048 * sizeof(float), stream);
  {
    dim3 gw1(1024 / 32, KP1 / 32);
    wconv_k<<<gw1, 256, 0, stream>>>(W1l, W1lT, FIN, 1024, KP1, acol, ccol, biasb);
    wconv_k<<<gw1, 256, 0, stream>>>(W1r, W1lT + (size_t)1024 * KP1, FIN, 1024, KP1, acol, ccol, biasb + 1024);
    dim3 g(2048 / 128, (n + 127) / 128);
    gemm_bf16_k<<<g, 256, 0, stream>>>(Abf, W1lT, xlb, xrb, biasb, n, 1024, KP1);
  }
  gat_edge_k<2><<<(n * 2 + 3) / 4, 256, 0, stream>>>(xlb, xrb, a1, b1, csr, offsets, hb, n, 0);

  hipMemsetAsync(s1, 0, 2 * 4096 * sizeof(float), stream);
  {
    dim3 g(1024 / 256, 160);
    col_stats_bf_k<<<g, 256, 0, stream>>>(hb, n, 1024, s1, s2);
    bn_fin_k<<<4, 256, 0, stream>>>(s1, s2, bn1_g, bn1_b, acol, ccol, 1024, invM);
    bn_apply8_k<<<(int)(((size_t)n * 1024 / 8 + 255) / 256), 256, 0, stream>>>(hb, acol, ccol, Abf, (size_t)n * 1024, 1024);
  }

  // ---- Layer 2 (K=1024 -> N=1024 combined) ----
  {
    dim3 gw2(512 / 32, 1024 / 32);
    wconv_k<<<gw2, 256, 0, stream>>>(W2l, WlT, 1024, 512, 1024, nullptr, nullptr, nullptr);
    wconv_k<<<gw2, 256, 0, stream>>>(W2r, WlT + (size_t)512 * 1024, 1024, 512, 1024, nullptr, nullptr, nullptr);
    dim3 g(1024 / 128, (n + 127) / 128);
    gemm_bf16_k<<<g, 256, 0, stream>>>(Abf, WlT, xlb, xrb, nullptr, n, 512, 1024);
  }
  gat_edge_k<1><<<(n + 3) / 4, 256, 0, stream>>>(xlb, xrb, a2, b2, csr, offsets, hb, n, 0);

  hipMemsetAsync(s1, 0, 2 * 4096 * sizeof(float), stream);
  {
    dim3 g(512 / 256, 160);
    col_stats_bf_k<<<g, 256, 0, stream>>>(hb, n, 512, s1, s2);
    bn_fin_k<<<2, 256, 0, stream>>>(s1, s2, bn2_g, bn2_b, acol, ccol, 512, invM);
    bn_apply8_k<<<(int)(((size_t)n * 512 / 8 + 255) / 256), 256, 0, stream>>>(hb, acol, ccol, Abf, (size_t)n * 512, 512);
  }

  // ---- Layer 3 (K=512 -> N=1024 combined) ----
  {
    dim3 gw3(512 / 32, 512 / 32);
    wconv_k<<<gw3, 256, 0, stream>>>(W3l, WlT, 512, 512, 512, nullptr, nullptr, nullptr);
    wconv_k<<<gw3, 256, 0, stream>>>(W3r, WlT + (size_t)512 * 512, 512, 512, 512, nullptr, nullptr, nullptr);
    dim3 g(1024 / 128, (n + 127) / 128);
    gemm_bf16_k<<<g, 256, 0, stream>>>(Abf, WlT, xlb, xrb, nullptr, n, 512, 512);
  }
  gat_edge_k<1><<<(n + 3) / 4, 256, 0, stream>>>(xlb, xrb, a3, b3, csr, offsets, hb, n, 0);

  hipMemsetAsync(s1, 0, 2 * 4096 * sizeof(float), stream);
  {
    dim3 g(512 / 256, 160);
    col_stats_bf_k<<<g, 256, 0, stream>>>(hb, n, 512, s1, s2);
    bn_fin_k<<<2, 256, 0, stream>>>(s1, s2, bn3_g, bn3_b, acol, ccol, 512, invM);
    bn_apply8_k<<<(int)(((size_t)n * 512 / 8 + 255) / 256), 256, 0, stream>>>(hb, acol, ccol, Abf, (size_t)n * 512, 512);
  }

  // ---- Layer 4 (K=512 -> N=1024 combined), relu fused into edge kernel ----
  {
    dim3 gw4(512 / 32, 512 / 32);
    wconv_k<<<gw4, 256, 0, stream>>>(W4l, WlT, 512, 512, 512, nullptr, nullptr, nullptr);
    wconv_k<<<gw4, 256, 0, stream>>>(W4r, WlT + (size_t)512 * 512, 512, 512, 512, nullptr, nullptr, nullptr);
    dim3 g(1024 / 128, (n + 127) / 128);
    gemm_bf16_k<<<g, 256, 0, stream>>>(Abf, WlT, xlb, xrb, nullptr, n, 512, 512);
  }
  gat_edge_k<1><<<(n + 3) / 4, 256, 0, stream>>>(xlb, xrb, a4, b4, csr, offsets, hb, n, 1);

  // ---- head + gather ----
  head_k<<<(n + 3) / 4, 256, 0, stream>>>(hb, Wh, bh, pred, n);
  gather_k<<<(NT + 255) / 256, 256, 0, stream>>>(pred, y, tidx, out, NT);
}